// Round 2
// baseline (38.404 us; speedup 1.0000x reference)
//
#include <hip/hip_runtime.h>

// LengthRegulator: out[b,c,t] = x[b,c,idx(b,t)] where idx(b,t) is the unique
// input token i whose segment owns output frame t (path is a 0/1 disjoint
// segment mask tiling [0,T_OUT), so bmm(x, path) == gather; exact).
//
// Fused single kernel, grid (T_OUT/256, B) = 256 blocks (1/CU), 512 threads
// (8 waves). Phase 1: wave w scans i in [32w,32w+32) with float4 path loads
// (1 KiB per wave-instr, deep unroll for HBM latency hiding); per-wave owner
// candidates merged via LDS. Phase 2: wave w writes channels c = w + 8j with
// float4 stores; x gathers are L1-resident (1 KiB row per (b,c)).

#define LR_B 32
#define LR_C 256
#define LR_TIN 256
#define LR_TOUT 2048
#define TILE_T 256
#define NWAVE 8
#define I_PER_WAVE (LR_TIN / NWAVE)   // 32
#define C_PER_WAVE (LR_C / NWAVE)     // 32

__global__ __launch_bounds__(512) void lr_fused2(const float* __restrict__ x,
                                                 const float* __restrict__ path,
                                                 float* __restrict__ out) {
    __shared__ int cand_lds[NWAVE][TILE_T];

    const int tid = threadIdx.x;
    const int w = tid >> 6;          // wave 0..7
    const int l = tid & 63;          // lane
    const int t0 = blockIdx.x * TILE_T;
    const int b = blockIdx.y;
    const int t4 = 4 * l;            // this lane's 4 t's within the tile

    // ---- phase 1: find owner token for each t in the tile ----
    const float* p = path + ((size_t)b * LR_TIN + (size_t)w * I_PER_WAVE) * LR_TOUT
                   + t0 + t4;
    int4 cand = make_int4(-1, -1, -1, -1);
#pragma unroll 8
    for (int ii = 0; ii < I_PER_WAVE; ++ii) {
        const float4 v = *reinterpret_cast<const float4*>(p + (size_t)ii * LR_TOUT);
        const int i = w * I_PER_WAVE + ii;
        if (v.x != 0.0f) cand.x = i;
        if (v.y != 0.0f) cand.y = i;
        if (v.z != 0.0f) cand.z = i;
        if (v.w != 0.0f) cand.w = i;
    }
    *reinterpret_cast<int4*>(&cand_lds[w][t4]) = cand;
    __syncthreads();

    // merge the 8 per-wave candidates (exactly one is >= 0 per t)
    int4 m = *reinterpret_cast<const int4*>(&cand_lds[0][t4]);
#pragma unroll
    for (int ww = 1; ww < NWAVE; ++ww) {
        const int4 c = *reinterpret_cast<const int4*>(&cand_lds[ww][t4]);
        m.x = max(m.x, c.x);
        m.y = max(m.y, c.y);
        m.z = max(m.z, c.z);
        m.w = max(m.w, c.w);
    }
    m.x = max(m.x, 0); m.y = max(m.y, 0); m.z = max(m.z, 0); m.w = max(m.w, 0);

    // ---- phase 2: gather-expand x into out ----
    const float* xb = x + (size_t)b * LR_C * LR_TIN;
    float* ob = out + (size_t)b * LR_C * LR_TOUT + t0 + t4;
#pragma unroll 4
    for (int j = 0; j < C_PER_WAVE; ++j) {
        const int c = w + NWAVE * j;
        const float* xr = xb + (size_t)c * LR_TIN;
        float4 o;
        o.x = xr[m.x];
        o.y = xr[m.y];
        o.z = xr[m.z];
        o.w = xr[m.w];
        *reinterpret_cast<float4*>(ob + (size_t)c * LR_TOUT) = o;
    }
}

extern "C" void kernel_launch(void* const* d_in, const int* in_sizes, int n_in,
                              void* d_out, int out_size, void* d_ws, size_t ws_size,
                              hipStream_t stream) {
    const float* x    = (const float*)d_in[0];   // [B, C, T_IN] fp32
    const float* path = (const float*)d_in[1];   // [B, T_IN, T_OUT] fp32
    float* out = (float*)d_out;                  // [B, C, T_OUT] fp32
    lr_fused2<<<dim3(LR_TOUT / TILE_T, LR_B), 512, 0, stream>>>(x, path, out);
}

// Round 3
// 31.367 us; speedup vs baseline: 1.2244x; 1.2244x over previous
//
#include <hip/hip_runtime.h>

// LengthRegulator: out[b,c,t] = x[b,c,idx(b,t)] where idx(b,t) is the unique
// input token i whose segment owns output frame t (path is a 0/1 disjoint
// segment mask tiling [0,T_OUT), so bmm(x, path) == gather; exact).
//
// K1 (idx build): i-scan split across blocks. Each block scans NI=16 tokens
// for a 1024-wide t-tile; exactly one block/lane sees path==1 for each t and
// does a plain store of the owner index (no atomics, no init needed: every t
// is owned exactly once). Grid 1024 blocks -> ~24 waves/CU, float4 loads
// fully unrolled (16 in flight/lane) -> latency fully hidden.
//
// K2 (gather-expand): 4 t per thread; int4 idx load + 4 L1-resident x gathers
// + float4 coalesced store. 16384 blocks -> full occupancy, write-BW-bound.

#define LR_B 32
#define LR_C 256
#define LR_TIN 256
#define LR_TOUT 2048

#define K1_THREADS 256
#define K1_TTILE   1024              // t per block (4 per thread)
#define K1_NI      16                // tokens scanned per block
#define K1_ISPLIT  (LR_TIN / K1_NI)  // 16

__global__ __launch_bounds__(K1_THREADS) void lr_idx2(const float* __restrict__ path,
                                                      int* __restrict__ idx) {
    const int t = blockIdx.x * K1_TTILE + threadIdx.x * 4;
    const int b = blockIdx.y;
    const int i0 = blockIdx.z * K1_NI;

    const float* p = path + ((size_t)b * LR_TIN + i0) * LR_TOUT + t;
    int4 cand = make_int4(-1, -1, -1, -1);
#pragma unroll
    for (int ii = 0; ii < K1_NI; ++ii) {
        const float4 v = *reinterpret_cast<const float4*>(p + (size_t)ii * LR_TOUT);
        const int i = i0 + ii;
        if (v.x != 0.0f) cand.x = i;
        if (v.y != 0.0f) cand.y = i;
        if (v.z != 0.0f) cand.z = i;
        if (v.w != 0.0f) cand.w = i;
    }
    int* ib = idx + b * LR_TOUT + t;
    if (cand.x >= 0) ib[0] = cand.x;
    if (cand.y >= 0) ib[1] = cand.y;
    if (cand.z >= 0) ib[2] = cand.z;
    if (cand.w >= 0) ib[3] = cand.w;
}

__global__ __launch_bounds__(256) void lr_gather2(const float* __restrict__ x,
                                                  const int* __restrict__ idx,
                                                  float* __restrict__ out) {
    const int lin = blockIdx.x * 256 + threadIdx.x;
    const int T4 = LR_TOUT / 4;
    const int t4 = (lin % T4) * 4;
    const int c  = (lin / T4) % LR_C;
    const int b  = lin / (T4 * LR_C);
    const int4 iv = *reinterpret_cast<const int4*>(idx + b * LR_TOUT + t4);
    const float* xrow = x + ((size_t)b * LR_C + c) * LR_TIN;
    float4 o;
    o.x = xrow[iv.x];
    o.y = xrow[iv.y];
    o.z = xrow[iv.z];
    o.w = xrow[iv.w];
    *reinterpret_cast<float4*>(out + ((size_t)b * LR_C + c) * LR_TOUT + t4) = o;
}

// Fallback if workspace is too small: R2's fused kernel (correct, slower).
__global__ __launch_bounds__(512) void lr_fused2(const float* __restrict__ x,
                                                 const float* __restrict__ path,
                                                 float* __restrict__ out) {
    __shared__ int cand_lds[8][256];
    const int tid = threadIdx.x;
    const int w = tid >> 6, l = tid & 63;
    const int t0 = blockIdx.x * 256, b = blockIdx.y;
    const int t4 = 4 * l;
    const float* p = path + ((size_t)b * LR_TIN + (size_t)w * 32) * LR_TOUT + t0 + t4;
    int4 cand = make_int4(-1, -1, -1, -1);
#pragma unroll 8
    for (int ii = 0; ii < 32; ++ii) {
        const float4 v = *reinterpret_cast<const float4*>(p + (size_t)ii * LR_TOUT);
        const int i = w * 32 + ii;
        if (v.x != 0.0f) cand.x = i;
        if (v.y != 0.0f) cand.y = i;
        if (v.z != 0.0f) cand.z = i;
        if (v.w != 0.0f) cand.w = i;
    }
    *reinterpret_cast<int4*>(&cand_lds[w][t4]) = cand;
    __syncthreads();
    int4 m = *reinterpret_cast<const int4*>(&cand_lds[0][t4]);
#pragma unroll
    for (int ww = 1; ww < 8; ++ww) {
        const int4 c = *reinterpret_cast<const int4*>(&cand_lds[ww][t4]);
        m.x = max(m.x, c.x); m.y = max(m.y, c.y);
        m.z = max(m.z, c.z); m.w = max(m.w, c.w);
    }
    m.x = max(m.x, 0); m.y = max(m.y, 0); m.z = max(m.z, 0); m.w = max(m.w, 0);
    const float* xb = x + (size_t)b * LR_C * LR_TIN;
    float* ob = out + (size_t)b * LR_C * LR_TOUT + t0 + t4;
#pragma unroll 4
    for (int j = 0; j < 32; ++j) {
        const int c = w + 8 * j;
        const float* xr = xb + (size_t)c * LR_TIN;
        float4 o;
        o.x = xr[m.x]; o.y = xr[m.y]; o.z = xr[m.z]; o.w = xr[m.w];
        *reinterpret_cast<float4*>(ob + (size_t)c * LR_TOUT) = o;
    }
}

extern "C" void kernel_launch(void* const* d_in, const int* in_sizes, int n_in,
                              void* d_out, int out_size, void* d_ws, size_t ws_size,
                              hipStream_t stream) {
    const float* x    = (const float*)d_in[0];   // [B, C, T_IN] fp32
    const float* path = (const float*)d_in[1];   // [B, T_IN, T_OUT] fp32
    float* out = (float*)d_out;                  // [B, C, T_OUT] fp32

    const size_t idx_bytes = (size_t)LR_B * LR_TOUT * sizeof(int);
    if (ws_size >= idx_bytes) {
        int* idx = (int*)d_ws;
        lr_idx2<<<dim3(LR_TOUT / K1_TTILE, LR_B, K1_ISPLIT), K1_THREADS, 0, stream>>>(path, idx);
        const int total_threads = LR_B * LR_C * (LR_TOUT / 4);
        lr_gather2<<<total_threads / 256, 256, 0, stream>>>(x, idx, out);
    } else {
        lr_fused2<<<dim3(LR_TOUT / 256, LR_B), 512, 0, stream>>>(x, path, out);
    }
}